// Round 5
// baseline (1007.580 us; speedup 1.0000x reference)
//
#include <hip/hip_runtime.h>
#include <cstdint>

#define BSZ 32
#define NVIS 1024
#define HID 256
#define TOKD 768
#define NCODE 2048
#define NPIX 32768

typedef unsigned short u16;
typedef _Float16 half8 __attribute__((ext_vector_type(8)));
typedef unsigned short ushort8 __attribute__((ext_vector_type(8)));
using f32x4 = __attribute__((ext_vector_type(4))) float;

#define AS1 __attribute__((address_space(1)))
#define AS3 __attribute__((address_space(3)))

__device__ __forceinline__ f32x4 mfmaF16(half8 a, half8 b, f32x4 c) {
  return __builtin_amdgcn_mfma_f32_16x16x32_f16(a, b, c, 0, 0, 0);
}

__device__ __forceinline__ unsigned long long pack_key(float d, int idx) {
  unsigned int b = __float_as_uint(d);
  b = (b & 0x80000000u) ? ~b : (b | 0x80000000u);  // monotonic float->uint
  return ((unsigned long long)b << 32) | (unsigned int)idx;
}

__device__ __forceinline__ void split16(float v, u16& h, u16& l) {
  union { _Float16 f; u16 u; } a, b;
  a.f = (_Float16)v;
  float hf = (float)a.f;
  b.f = (_Float16)(v - hf);
  h = a.u; l = b.u;
}

// ================= prep1: all weights-only precompute, one launch =================
__global__ __launch_bounds__(256)
void prep1(const float* __restrict__ cb, const float* __restrict__ wh,
           const float* __restrict__ wt, const float* __restrict__ wp,
           const float* __restrict__ wg, const float* __restrict__ bp,
           u16* __restrict__ cbh, u16* __restrict__ cbl,
           u16* __restrict__ whh, u16* __restrict__ whl,
           float* __restrict__ cbn, float* __restrict__ Mm, float* __restrict__ uv,
           float* __restrict__ Gt, float* __restrict__ g2,
           float* __restrict__ ct0, float* __restrict__ cg) {
  const int bid = blockIdx.x, tid = threadIdx.x;
  if (bid < 6144) {                       // split cb
    int i = bid*256 + tid;
    u16 h, l; split16(cb[i], h, l);
    cbh[i] = h; cbl[i] = l;
  } else if (bid < 6912) {                // split w_head
    int i = (bid - 6144)*256 + tid;
    u16 h, l; split16(wh[i], h, l);
    whh[i] = h; whl[i] = l;
  } else if (bid < 7424) {                // code norms
    int n = (bid - 6912)*4 + (tid >> 6);
    int lane = tid & 63;
    float a = 0.f;
#pragma unroll
    for (int i = 0; i < 12; ++i) { float v = cb[(long)n*TOKD + lane + 64*i]; a += v*v; }
#pragma unroll
    for (int off = 32; off; off >>= 1) a += __shfl_down(a, off);
    if (lane == 0) cbn[n] = a;
  } else if (bid < 7680) {                // make_M
    int c2 = bid - 7424, c1 = tid;
    float acc = 0.f;
    for (int t = 0; t < TOKD; ++t) acc += wh[t*HID + c1] * wt[(long)c2*TOKD + t];
    Mm[c1*HID + c2] = acc;
  } else if (bid < 7682) {                // make_u
    int o = bid - 7680, c1 = tid;
    float acc = 0.f;
    for (int t = 0; t < TOKD; ++t) acc += wh[t*HID + c1] * wg[o*(2*TOKD) + TOKD + t];
    uv[o*HID + c1] = acc;
  } else if (bid < 8450) {                // make_Gt
    int rbid = bid - 7682;
    int c = rbid & 255, part = rbid >> 8;
    int tp = part*256 + tid;
    float acc = 0.f;
    for (int t = 0; t < TOKD; ++t) acc += wt[(long)c*TOKD + t] * wp[(long)t*TOKD + tp];
    Gt[(long)tp*HID + c] = acc;
  } else if (bid < 8453) {                // g2
    int tp = (bid - 8450)*256 + tid;
    float a0 = 0.f, a1 = 0.f;
    for (int t = 0; t < TOKD; ++t) {
      float wv = wp[(long)t*TOKD + tp];
      a0 += wv * wg[t];
      a1 += wv * wg[2*TOKD + t];
    }
    g2[tp] = a0; g2[TOKD + tp] = a1;
  } else if (bid < 8454) {                // ct0
    int c = tid;
    float a = 0.f;
    for (int t = 0; t < TOKD; ++t) a += bp[t] * wt[(long)c*TOKD + t];
    ct0[c] = a;
  } else {                                // cg
    int o = tid >> 6, lane = tid & 63;
    if (o < 2) {
      float a = 0.f;
      for (int t = lane; t < TOKD; t += 64) a += bp[t] * wg[o*(2*TOKD) + t];
#pragma unroll
      for (int off = 32; off; off >>= 1) a += __shfl_down(a, off);
      if (lane == 0) cg[o] = a;
    }
  }
}

// ================= prep2: tailcode + gA from shared cb tile =================
__global__ __launch_bounds__(256)
void prep2(const float* __restrict__ cb, const float* __restrict__ Gt,
           const float* __restrict__ ct0, const float* __restrict__ g2,
           const float* __restrict__ cg, float* __restrict__ tc,
           float* __restrict__ gA) {
  __shared__ float cbs[8][TOKD];
  const int n0 = blockIdx.x * 8, tid = threadIdx.x;
  for (int i = tid; i < 8*TOKD; i += 256) cbs[i / TOKD][i % TOKD] = cb[(long)n0*TOKD + i];
  __syncthreads();
  float acc[8] = {};
  for (int t = 0; t < TOKD; ++t) {
    float gv = Gt[(long)t*HID + tid];
#pragma unroll
    for (int i = 0; i < 8; ++i) acc[i] += cbs[i][t] * gv;
  }
  float c0v = ct0[tid];
#pragma unroll
  for (int i = 0; i < 8; ++i) tc[(long)(n0+i)*HID + tid] = acc[i] + c0v;
  {
    int i = tid >> 5, l32 = tid & 31;
    float a0 = 0.f, a1 = 0.f;
    for (int t = l32; t < TOKD; t += 32) {
      float cv = cbs[i][t];
      a0 += cv * g2[t];
      a1 += cv * g2[TOKD + t];
    }
#pragma unroll
    for (int off = 16; off; off >>= 1) { a0 += __shfl_down(a0, off); a1 += __shfl_down(a1, off); }
    if (l32 == 0) { gA[n0+i] = a0 + cg[0]; gA[NCODE + n0+i] = a1 + cg[1]; }
  }
}

// ================= head GEMM (MFMA fp16 3-term) with coalesced stores =================
__global__ __launch_bounds__(256)
void head_mfma(const u16* __restrict__ whh, const u16* __restrict__ whl,
               const float* __restrict__ src,
               u16* __restrict__ xqh, u16* __restrict__ xql) {
  __shared__ u16 SM[32768] __attribute__((aligned(16)));   // 64 KB
  u16* Ah = SM;            // [2][4096]
  u16* Al = SM + 8192;
  u16* Bh = SM + 16384;
  u16* Bl = SM + 24576;
  const int tid = threadIdx.x, lane = tid & 63, w = tid >> 6;
  const int n = lane & 15, q = lane >> 4;
  const int rh = w & 1, ch = w >> 1;
  const int obase = blockIdx.x * 128, pbase = blockIdx.y * 128, b = blockIdx.z;

  auto stageA = [&](int kc, int buf) {
#pragma unroll
    for (int is = 0; is < 2; ++is) {
      int c = is*256 + tid;
      int t = c >> 6, qq = (c >> 4) & 3, nn = c & 15;
      long off = (long)(obase + t*16 + nn)*HID + kc*32 + qq*8;
      __builtin_amdgcn_global_load_lds((AS1 void*)(whh + off),
          (AS3 void*)&Ah[buf*4096 + c*8], 16, 0, 0);
      __builtin_amdgcn_global_load_lds((AS1 void*)(whl + off),
          (AS3 void*)&Al[buf*4096 + c*8], 16, 0, 0);
    }
  };
  auto stageB = [&](int kc, int buf) {
#pragma unroll
    for (int is = 0; is < 2; ++is) {
      int c = is*256 + tid;
      int t = c >> 6, qq = (c >> 4) & 3, nn = c & 15;
      const float* gp = src + ((long)(pbase + t*16 + nn)*BSZ + b)*HID + kc*32 + qq*8;
      float4 v0 = *(const float4*)gp;
      float4 v1 = *(const float4*)(gp + 4);
      float vv[8] = {v0.x, v0.y, v0.z, v0.w, v1.x, v1.y, v1.z, v1.w};
      ushort8 hv, lv;
#pragma unroll
      for (int j = 0; j < 8; ++j) { u16 hs, ls; split16(vv[j], hs, ls); hv[j] = hs; lv[j] = ls; }
      *(ushort8*)&Bh[buf*4096 + c*8] = hv;
      *(ushort8*)&Bl[buf*4096 + c*8] = lv;
    }
  };

  f32x4 acc[4][4];
#pragma unroll
  for (int i = 0; i < 4; ++i)
#pragma unroll
    for (int j = 0; j < 4; ++j) acc[i][j] = (f32x4){0.f, 0.f, 0.f, 0.f};

  stageA(0, 0); stageB(0, 0);
  __syncthreads();

  for (int kt = 0; kt < HID/32; ++kt) {
    const int buf = kt & 1;
    if (kt + 1 < HID/32) { stageA(kt + 1, buf ^ 1); stageB(kt + 1, buf ^ 1); }
    half8 af[4][2], bf[4][2];
#pragma unroll
    for (int rt = 0; rt < 4; ++rt) {
      int idx = buf*4096 + ((rh*4 + rt)*64 + q*16 + n)*8;
      af[rt][0] = *(const half8*)&Ah[idx];
      af[rt][1] = *(const half8*)&Al[idx];
    }
#pragma unroll
    for (int ct = 0; ct < 4; ++ct) {
      int idx = buf*4096 + ((ch*4 + ct)*64 + q*16 + n)*8;
      bf[ct][0] = *(const half8*)&Bh[idx];
      bf[ct][1] = *(const half8*)&Bl[idx];
    }
#pragma unroll
    for (int rt = 0; rt < 4; ++rt)
#pragma unroll
      for (int ct = 0; ct < 4; ++ct) {
        acc[rt][ct] = mfmaF16(af[rt][0], bf[ct][0], acc[rt][ct]);
        acc[rt][ct] = mfmaF16(af[rt][0], bf[ct][1], acc[rt][ct]);
        acc[rt][ct] = mfmaF16(af[rt][1], bf[ct][0], acc[rt][ct]);
      }
    __syncthreads();
  }

#pragma unroll
  for (int pass = 0; pass < 2; ++pass) {
    u16* dst = pass ? xql : xqh;
#pragma unroll
    for (int rt = 0; rt < 4; ++rt)
#pragma unroll
      for (int ct = 0; ct < 4; ++ct)
#pragma unroll
        for (int reg = 0; reg < 4; ++reg) {
          u16 hs, ls; split16(acc[rt][ct][reg], hs, ls);
          int ol = rh*64 + rt*16 + q*4 + reg;
          int pl = ch*64 + ct*16 + n;
          SM[ol*136 + pl] = pass ? ls : hs;
        }
    __syncthreads();
#pragma unroll
    for (int s = 0; s < 8; ++s) {
      int cc = tid*8 + s;
      int o = cc >> 4, p8 = cc & 15;
      ushort8 v = *(const ushort8*)&SM[o*136 + p8*8];
      *(ushort8*)(dst + ((long)b*TOKD + obase + o)*NVIS + pbase + p8*8) = v;
    }
    __syncthreads();
  }
}

// ================= VQ: 256x128 tile, A in registers (direct global), B via LDS =================
// grid 2048 (bid = rb*16 + cblk -> XCD = cblk%8, B slice L2-resident), 256 threads.
// K = 2304 = 3 segments of 768: [xh*eh | xl*eh | xh*el]. 72 kc-steps of 32.
__global__ __launch_bounds__(256, 2)
void vq_mfma(const u16* __restrict__ xqh, const u16* __restrict__ xql,
             const u16* __restrict__ cbh, const u16* __restrict__ cbl,
             const float* __restrict__ cbn, unsigned long long* __restrict__ keys) {
  __shared__ u16 Bsm[2][4096] __attribute__((aligned(16)));
  __shared__ float cbns[128];
  const int bid = blockIdx.x;
  const int rb = bid >> 4, cblk = bid & 15;
  const int rowbase = rb * 256, codebase = cblk * 128;
  const int tid = threadIdx.x, lane = tid & 63, w = tid >> 6;
  const int n = lane & 15, q = lane >> 4;
  const int wr = w & 1, wc = w >> 1;

  if (tid < 128) cbns[tid] = cbn[codebase + tid];

  const long arowb = (long)(rowbase + wr*128 + n) * TOKD + q*8;
  const u16* aph = xqh + arowb;
  const u16* apl = xql + arowb;

  half8 A0[8], A1[8];
  auto loadA = [&](int kc, half8 (&dst)[8]) {
    if (kc >= 72) return;
    const int seg = (kc >= 48) ? 2 : (kc >= 24 ? 1 : 0);
    const int kk = kc - seg*24;
    const u16* p = ((seg == 1) ? apl : aph) + kk*32;
#pragma unroll
    for (int rt = 0; rt < 8; ++rt)
      dst[rt] = *(const half8*)(p + (long)rt*(16*TOKD));
  };
  auto stageB = [&](int kc, int buf) {
    const int seg = (kc >= 48) ? 2 : (kc >= 24 ? 1 : 0);
    const int kk = kc - seg*24;
    const u16* bb = (seg == 2) ? cbl : cbh;
#pragma unroll
    for (int is = 0; is < 2; ++is) {
      int c = is*256 + tid;
      int tt = c >> 6, qq = (c >> 4) & 3, nn = c & 15;
      long boff = (long)(codebase + tt*16 + nn)*TOKD + kk*32 + qq*8;
      __builtin_amdgcn_global_load_lds((AS1 void*)(bb + boff),
          (AS3 void*)&Bsm[buf][c*8], 16, 0, 0);
    }
  };

  f32x4 acc[8][4];
#pragma unroll
  for (int a = 0; a < 8; ++a)
#pragma unroll
    for (int b2 = 0; b2 < 4; ++b2) acc[a][b2] = (f32x4){0.f, 0.f, 0.f, 0.f};

  auto compute = [&](half8 (&Ar)[8], int buf) {
    half8 bf[4];
#pragma unroll
    for (int ct = 0; ct < 4; ++ct)
      bf[ct] = *(const half8*)&Bsm[buf][((wc*4 + ct)*64 + q*16 + n)*8];
#pragma unroll
    for (int rt = 0; rt < 8; ++rt)
#pragma unroll
      for (int ct = 0; ct < 4; ++ct)
        acc[rt][ct] = mfmaF16(Ar[rt], bf[ct], acc[rt][ct]);
  };

  loadA(0, A0);
  stageB(0, 0);
  __syncthreads();

  for (int kc2 = 0; kc2 < 36; ++kc2) {
    const int kc = kc2 * 2;
    loadA(kc + 1, A1);
    stageB(kc + 1, 1);
    compute(A0, 0);
    __syncthreads();
    loadA(kc + 2, A0);
    if (kc + 2 < 72) stageB(kc + 2, 0);
    compute(A1, 1);
    __syncthreads();
  }

  // fused argmin: lane holds d for row = wr*128+rt*16+q*4+reg, code = wc*64+ct*16+n
#pragma unroll
  for (int rt = 0; rt < 8; ++rt) {
#pragma unroll
    for (int reg = 0; reg < 4; ++reg) {
      float bd = 3.4e38f; int bi = 0;
#pragma unroll
      for (int ct = 0; ct < 4; ++ct) {
        float d = cbns[wc*64 + ct*16 + n] - 2.0f * acc[rt][ct][reg];
        int code = codebase + wc*64 + ct*16 + n;
        if (d < bd) { bd = d; bi = code; }
      }
      unsigned long long k = pack_key(bd, bi);
      unsigned long long v;
      v = __shfl_xor(k, 1); k = (v < k) ? v : k;
      v = __shfl_xor(k, 2); k = (v < k) ? v : k;
      v = __shfl_xor(k, 4); k = (v < k) ? v : k;
      v = __shfl_xor(k, 8); k = (v < k) ? v : k;
      if (n == 0) {
        int row = rowbase + wr*128 + rt*16 + q*4 + reg;
        atomicMin(&keys[row], k);
      }
    }
  }
}

__global__ void unpack_idx(const unsigned long long* __restrict__ keys,
                           int* __restrict__ idxv, float* __restrict__ outIdx) {
  int r = blockIdx.x * 256 + threadIdx.x;
  unsigned long long u = keys[r];
  int id = (int)(unsigned int)(u & 0xFFFFFFFFull);
  idxv[r] = id;
  outIdx[r] = (float)id;
}

// ================= fused gate + tail output (verified round 0/3/4) =================
__global__ __launch_bounds__(256)
void fuse_out(const float* __restrict__ src, const int* __restrict__ idxv,
              const float* __restrict__ gA, const float* __restrict__ uvec,
              const float* __restrict__ Mm, const float* __restrict__ tailcode,
              float* __restrict__ out) {
  __shared__ float ss[32][257];
  __shared__ float s0s[32];
  __shared__ int ids[32];
  const int tid = threadIdx.x;
  const int rb = blockIdx.x * 32;
  const int b = rb >> 10;
  const int p0 = rb & 1023;
#pragma unroll
  for (int qq = 0; qq < 32; ++qq)
    ss[qq][tid] = src[(long)(p0 + qq) * (BSZ*HID) + b*HID + tid];
  if (tid < 32) ids[tid] = idxv[rb + tid];
  __syncthreads();
  {
    const int wv = tid >> 6, lane = tid & 63;
    for (int qq = 0; qq < 8; ++qq) {
      int qp = wv*8 + qq;
      float a0 = 0.f, a1 = 0.f;
#pragma unroll
      for (int i = 0; i < 4; ++i) {
        float v = ss[qp][lane + 64*i];
        a0 += v * uvec[lane + 64*i];
        a1 += v * uvec[HID + lane + 64*i];
      }
#pragma unroll
      for (int off = 32; off; off >>= 1) { a0 += __shfl_down(a0, off); a1 += __shfl_down(a1, off); }
      if (lane == 0) {
        int id = ids[qp];
        float l0 = gA[id] + a0;
        float l1 = gA[NCODE + id] + a1;
        s0s[qp] = 1.0f / (1.0f + expf(l1 - l0));
      }
    }
  }
  __syncthreads();
  const int qg = tid >> 5, cg = tid & 31;
  const int q0 = qg * 4, c0 = cg * 8;
  float acc[4][8] = {};
  for (int cp = 0; cp < HID; ++cp) {
    float4 m0 = *(const float4*)(Mm + cp*HID + c0);
    float4 m1 = *(const float4*)(Mm + cp*HID + c0 + 4);
    float mm[8] = {m0.x,m0.y,m0.z,m0.w,m1.x,m1.y,m1.z,m1.w};
#pragma unroll
    for (int i = 0; i < 4; ++i) {
      float sv = ss[q0+i][cp];
#pragma unroll
      for (int j = 0; j < 8; ++j) acc[i][j] += sv * mm[j];
    }
  }
#pragma unroll
  for (int i = 0; i < 4; ++i) {
    int qp = q0 + i;
    int id = ids[qp];
    float s0 = s0s[qp], s1 = 1.0f - s0;
    const float* tc = tailcode + (long)id*HID + c0;
    float* op = out + (long)(p0+qp)*(BSZ*HID) + b*HID + c0;
    float4 o0, o1;
    o0.x = s0*tc[0] + s1*acc[i][0]; o0.y = s0*tc[1] + s1*acc[i][1];
    o0.z = s0*tc[2] + s1*acc[i][2]; o0.w = s0*tc[3] + s1*acc[i][3];
    o1.x = s0*tc[4] + s1*acc[i][4]; o1.y = s0*tc[5] + s1*acc[i][5];
    o1.z = s0*tc[6] + s1*acc[i][6]; o1.w = s0*tc[7] + s1*acc[i][7];
    *(float4*)(op) = o0; *(float4*)(op+4) = o1;
  }
}

// ================= launch =================
extern "C" void kernel_launch(void* const* d_in, const int* in_sizes, int n_in,
                              void* d_out, int out_size, void* d_ws, size_t ws_size,
                              hipStream_t stream) {
  const float* src    = (const float*)d_in[0];
  const float* cb     = (const float*)d_in[1];
  const float* w_head = (const float*)d_in[2];
  const float* w_tail = (const float*)d_in[3];
  const float* w_pos  = (const float*)d_in[4];
  const float* b_pos  = (const float*)d_in[5];
  const float* w_gate = (const float*)d_in[6];
  float* out = (float*)d_out;

  char* wsp = (char*)d_ws;
  size_t off = 0;
  auto alloc = [&](size_t bytes) {
    off = (off + 255) & ~(size_t)255;
    void* p = wsp + off; off += bytes; return p;
  };
  u16* xqh = (u16*)alloc((size_t)BSZ*TOKD*NVIS*2);  // 50.3 MB
  u16* xql = (u16*)alloc((size_t)BSZ*TOKD*NVIS*2);  // 50.3 MB
  u16* cbh = (u16*)alloc((size_t)NCODE*TOKD*2);
  u16* cbl = (u16*)alloc((size_t)NCODE*TOKD*2);
  u16* whh = (u16*)alloc((size_t)TOKD*HID*2);
  u16* whl = (u16*)alloc((size_t)TOKD*HID*2);
  float* cbn      = (float*)alloc((size_t)NCODE*4);
  float* Gt       = (float*)alloc((size_t)TOKD*HID*4);
  float* g2       = (float*)alloc((size_t)2*TOKD*4);
  float* ct0      = (float*)alloc((size_t)HID*4);
  float* cg       = (float*)alloc((size_t)2*4);
  float* tailcode = (float*)alloc((size_t)NCODE*HID*4);
  float* gA       = (float*)alloc((size_t)2*NCODE*4);
  float* Mm       = (float*)alloc((size_t)HID*HID*4);
  float* uvec     = (float*)alloc((size_t)2*HID*4);
  unsigned long long* keys = (unsigned long long*)alloc((size_t)NPIX*8);
  int* idxv       = (int*)alloc((size_t)NPIX*4);
  (void)ws_size; (void)in_sizes; (void)n_in; (void)out_size;

  prep1<<<8455, 256, 0, stream>>>(cb, w_head, w_tail, w_pos, w_gate, b_pos,
                                  cbh, cbl, whh, whl, cbn, Mm, uvec, Gt, g2, ct0, cg);
  prep2<<<NCODE/8, 256, 0, stream>>>(cb, Gt, ct0, g2, cg, tailcode, gA);

  head_mfma<<<dim3(TOKD/128, NVIS/128, BSZ), 256, 0, stream>>>(whh, whl, src, xqh, xql);

  hipMemsetAsync(keys, 0xFF, (size_t)NPIX*8, stream);
  vq_mfma<<<2048, 256, 0, stream>>>(xqh, xql, cbh, cbl, cbn, keys);
  unpack_idx<<<NPIX/256, 256, 0, stream>>>(keys, idxv, out + (size_t)NVIS*BSZ*HID);

  fuse_out<<<NPIX/32, 256, 0, stream>>>(src, idxv, gA, uvec, Mm, tailcode, out);
}

// Round 6
// 763.380 us; speedup vs baseline: 1.3199x; 1.3199x over previous
//
#include <hip/hip_runtime.h>
#include <cstdint>

#define BSZ 32
#define NVIS 1024
#define HID 256
#define TOKD 768
#define NCODE 2048
#define NPIX 32768

typedef unsigned short u16;
typedef _Float16 half8 __attribute__((ext_vector_type(8)));
typedef unsigned short ushort8 __attribute__((ext_vector_type(8)));
using f32x4 = __attribute__((ext_vector_type(4))) float;

#define AS1 __attribute__((address_space(1)))
#define AS3 __attribute__((address_space(3)))

__device__ __forceinline__ f32x4 mfmaF16(half8 a, half8 b, f32x4 c) {
  return __builtin_amdgcn_mfma_f32_16x16x32_f16(a, b, c, 0, 0, 0);
}

__device__ __forceinline__ unsigned long long pack_key(float d, int idx) {
  unsigned int b = __float_as_uint(d);
  b = (b & 0x80000000u) ? ~b : (b | 0x80000000u);  // monotonic float->uint
  return ((unsigned long long)b << 32) | (unsigned int)idx;
}

__device__ __forceinline__ void split16(float v, u16& h, u16& l) {
  union { _Float16 f; u16 u; } a, b;
  a.f = (_Float16)v;
  float hf = (float)a.f;
  b.f = (_Float16)(v - hf);
  h = a.u; l = b.u;
}

// ================= prep1: all weights-only precompute, one launch =================
__global__ __launch_bounds__(256)
void prep1(const float* __restrict__ cb, const float* __restrict__ wh,
           const float* __restrict__ wt, const float* __restrict__ wp,
           const float* __restrict__ wg, const float* __restrict__ bp,
           u16* __restrict__ cbh, u16* __restrict__ cbl,
           u16* __restrict__ whh, u16* __restrict__ whl,
           float* __restrict__ cbn, float* __restrict__ Mm, float* __restrict__ uv,
           float* __restrict__ Gt, float* __restrict__ g2,
           float* __restrict__ ct0, float* __restrict__ cg) {
  const int bid = blockIdx.x, tid = threadIdx.x;
  if (bid < 6144) {                       // split cb
    int i = bid*256 + tid;
    u16 h, l; split16(cb[i], h, l);
    cbh[i] = h; cbl[i] = l;
  } else if (bid < 6912) {                // split w_head
    int i = (bid - 6144)*256 + tid;
    u16 h, l; split16(wh[i], h, l);
    whh[i] = h; whl[i] = l;
  } else if (bid < 7424) {                // code norms
    int n = (bid - 6912)*4 + (tid >> 6);
    int lane = tid & 63;
    float a = 0.f;
#pragma unroll
    for (int i = 0; i < 12; ++i) { float v = cb[(long)n*TOKD + lane + 64*i]; a += v*v; }
#pragma unroll
    for (int off = 32; off; off >>= 1) a += __shfl_down(a, off);
    if (lane == 0) cbn[n] = a;
  } else if (bid < 7680) {                // make_M
    int c2 = bid - 7424, c1 = tid;
    float acc = 0.f;
    for (int t = 0; t < TOKD; ++t) acc += wh[t*HID + c1] * wt[(long)c2*TOKD + t];
    Mm[c1*HID + c2] = acc;
  } else if (bid < 7682) {                // make_u
    int o = bid - 7680, c1 = tid;
    float acc = 0.f;
    for (int t = 0; t < TOKD; ++t) acc += wh[t*HID + c1] * wg[o*(2*TOKD) + TOKD + t];
    uv[o*HID + c1] = acc;
  } else if (bid < 8450) {                // make_Gt
    int rbid = bid - 7682;
    int c = rbid & 255, part = rbid >> 8;
    int tp = part*256 + tid;
    float acc = 0.f;
    for (int t = 0; t < TOKD; ++t) acc += wt[(long)c*TOKD + t] * wp[(long)t*TOKD + tp];
    Gt[(long)tp*HID + c] = acc;
  } else if (bid < 8453) {                // g2
    int tp = (bid - 8450)*256 + tid;
    float a0 = 0.f, a1 = 0.f;
    for (int t = 0; t < TOKD; ++t) {
      float wv = wp[(long)t*TOKD + tp];
      a0 += wv * wg[t];
      a1 += wv * wg[2*TOKD + t];
    }
    g2[tp] = a0; g2[TOKD + tp] = a1;
  } else if (bid < 8454) {                // ct0
    int c = tid;
    float a = 0.f;
    for (int t = 0; t < TOKD; ++t) a += bp[t] * wt[(long)c*TOKD + t];
    ct0[c] = a;
  } else {                                // cg
    int o = tid >> 6, lane = tid & 63;
    if (o < 2) {
      float a = 0.f;
      for (int t = lane; t < TOKD; t += 64) a += bp[t] * wg[o*(2*TOKD) + t];
#pragma unroll
      for (int off = 32; off; off >>= 1) a += __shfl_down(a, off);
      if (lane == 0) cg[o] = a;
    }
  }
}

// ================= prep2: tailcode + gA from shared cb tile =================
__global__ __launch_bounds__(256)
void prep2(const float* __restrict__ cb, const float* __restrict__ Gt,
           const float* __restrict__ ct0, const float* __restrict__ g2,
           const float* __restrict__ cg, float* __restrict__ tc,
           float* __restrict__ gA) {
  __shared__ float cbs[8][TOKD];
  const int n0 = blockIdx.x * 8, tid = threadIdx.x;
  for (int i = tid; i < 8*TOKD; i += 256) cbs[i / TOKD][i % TOKD] = cb[(long)n0*TOKD + i];
  __syncthreads();
  float acc[8] = {};
  for (int t = 0; t < TOKD; ++t) {
    float gv = Gt[(long)t*HID + tid];
#pragma unroll
    for (int i = 0; i < 8; ++i) acc[i] += cbs[i][t] * gv;
  }
  float c0v = ct0[tid];
#pragma unroll
  for (int i = 0; i < 8; ++i) tc[(long)(n0+i)*HID + tid] = acc[i] + c0v;
  {
    int i = tid >> 5, l32 = tid & 31;
    float a0 = 0.f, a1 = 0.f;
    for (int t = l32; t < TOKD; t += 32) {
      float cv = cbs[i][t];
      a0 += cv * g2[t];
      a1 += cv * g2[TOKD + t];
    }
#pragma unroll
    for (int off = 16; off; off >>= 1) { a0 += __shfl_down(a0, off); a1 += __shfl_down(a1, off); }
    if (l32 == 0) { gA[n0+i] = a0 + cg[0]; gA[NCODE + n0+i] = a1 + cg[1]; }
  }
}

// ================= head GEMM (round-4 verified, row-major coalesced stores) =================
__global__ __launch_bounds__(256)
void head_mfma(const u16* __restrict__ whh, const u16* __restrict__ whl,
               const float* __restrict__ src,
               u16* __restrict__ xqh, u16* __restrict__ xql) {
  __shared__ u16 SM[32768] __attribute__((aligned(16)));   // 64 KB
  u16* Ah = SM;            // [2][4096]
  u16* Al = SM + 8192;
  u16* Bh = SM + 16384;
  u16* Bl = SM + 24576;
  const int tid = threadIdx.x, lane = tid & 63, w = tid >> 6;
  const int n = lane & 15, q = lane >> 4;
  const int rh = w & 1, ch = w >> 1;
  const int obase = blockIdx.x * 128, pbase = blockIdx.y * 128, b = blockIdx.z;

  auto stageA = [&](int kc, int buf) {
#pragma unroll
    for (int is = 0; is < 2; ++is) {
      int c = is*256 + tid;
      int t = c >> 6, qq = (c >> 4) & 3, nn = c & 15;
      long off = (long)(obase + t*16 + nn)*HID + kc*32 + qq*8;
      __builtin_amdgcn_global_load_lds((AS1 void*)(whh + off),
          (AS3 void*)&Ah[buf*4096 + c*8], 16, 0, 0);
      __builtin_amdgcn_global_load_lds((AS1 void*)(whl + off),
          (AS3 void*)&Al[buf*4096 + c*8], 16, 0, 0);
    }
  };
  auto stageB = [&](int kc, int buf) {
#pragma unroll
    for (int is = 0; is < 2; ++is) {
      int c = is*256 + tid;
      int t = c >> 6, qq = (c >> 4) & 3, nn = c & 15;
      const float* gp = src + ((long)(pbase + t*16 + nn)*BSZ + b)*HID + kc*32 + qq*8;
      float4 v0 = *(const float4*)gp;
      float4 v1 = *(const float4*)(gp + 4);
      float vv[8] = {v0.x, v0.y, v0.z, v0.w, v1.x, v1.y, v1.z, v1.w};
      ushort8 hv, lv;
#pragma unroll
      for (int j = 0; j < 8; ++j) { u16 hs, ls; split16(vv[j], hs, ls); hv[j] = hs; lv[j] = ls; }
      *(ushort8*)&Bh[buf*4096 + c*8] = hv;
      *(ushort8*)&Bl[buf*4096 + c*8] = lv;
    }
  };

  f32x4 acc[4][4];
#pragma unroll
  for (int i = 0; i < 4; ++i)
#pragma unroll
    for (int j = 0; j < 4; ++j) acc[i][j] = (f32x4){0.f, 0.f, 0.f, 0.f};

  stageA(0, 0); stageB(0, 0);
  __syncthreads();

  for (int kt = 0; kt < HID/32; ++kt) {
    const int buf = kt & 1;
    if (kt + 1 < HID/32) { stageA(kt + 1, buf ^ 1); stageB(kt + 1, buf ^ 1); }
    half8 af[4][2], bf[4][2];
#pragma unroll
    for (int rt = 0; rt < 4; ++rt) {
      int idx = buf*4096 + ((rh*4 + rt)*64 + q*16 + n)*8;
      af[rt][0] = *(const half8*)&Ah[idx];
      af[rt][1] = *(const half8*)&Al[idx];
    }
#pragma unroll
    for (int ct = 0; ct < 4; ++ct) {
      int idx = buf*4096 + ((ch*4 + ct)*64 + q*16 + n)*8;
      bf[ct][0] = *(const half8*)&Bh[idx];
      bf[ct][1] = *(const half8*)&Bl[idx];
    }
#pragma unroll
    for (int rt = 0; rt < 4; ++rt)
#pragma unroll
      for (int ct = 0; ct < 4; ++ct) {
        acc[rt][ct] = mfmaF16(af[rt][0], bf[ct][0], acc[rt][ct]);
        acc[rt][ct] = mfmaF16(af[rt][0], bf[ct][1], acc[rt][ct]);
        acc[rt][ct] = mfmaF16(af[rt][1], bf[ct][0], acc[rt][ct]);
      }
    __syncthreads();
  }

#pragma unroll
  for (int pass = 0; pass < 2; ++pass) {
    u16* dst = pass ? xql : xqh;
#pragma unroll
    for (int rt = 0; rt < 4; ++rt)
#pragma unroll
      for (int ct = 0; ct < 4; ++ct)
#pragma unroll
        for (int reg = 0; reg < 4; ++reg) {
          u16 hs, ls; split16(acc[rt][ct][reg], hs, ls);
          int ol = rh*64 + rt*16 + q*4 + reg;
          int pl = ch*64 + ct*16 + n;
          SM[ol*136 + pl] = pass ? ls : hs;
        }
    __syncthreads();
#pragma unroll
    for (int s = 0; s < 8; ++s) {
      int cc = tid*8 + s;
      int o = cc >> 4, p8 = cc & 15;
      ushort8 v = *(const ushort8*)&SM[o*136 + p8*8];
      *(ushort8*)(dst + ((long)b*TOKD + obase + o)*NVIS + pbase + p8*8) = v;
    }
    __syncthreads();
  }
}

// ================= retile: in-place row-major -> MFMA-fragment-tiled =================
// Tile = 16 rows x 768 k = 24 KB, same byte range in both layouts (in-place safe).
// Tiled chunk (tile, kc): 1 KB = [lane=q*16+n][8 elems], elem (row n, k=kc*32+q*8+j).
__global__ __launch_bounds__(256)
void retile(u16* __restrict__ bufH, u16* __restrict__ bufL) {
  __shared__ u16 T[96*136] __attribute__((aligned(16)));
  const long tile = blockIdx.x;
  const int tid = threadIdx.x;
#pragma unroll
  for (int pass = 0; pass < 2; ++pass) {
    u16* buf = pass ? bufL : bufH;
    if (pass) __syncthreads();
    // read row-major: g = i*256+tid -> row = g/96, c16 = g%96 (16B groups)
#pragma unroll
    for (int i = 0; i < 6; ++i) {
      int g = i*256 + tid;
      int row = g / 96, c16 = g % 96;
      ushort8 v = *(const ushort8*)(buf + tile*12288 + row*768 + c16*8);
      *(ushort8*)&T[c16*136 + row*8] = v;
    }
    __syncthreads();
    // write tiled: g = kc*64 + lane' ; lane' = q*16+n -> LDS (c16=kc*4+q, row=n)
#pragma unroll
    for (int i = 0; i < 6; ++i) {
      int g = i*256 + tid;
      int kc = g >> 6, lp = g & 63;
      int q = lp >> 4, n = lp & 15;
      ushort8 v = *(const ushort8*)&T[(kc*4 + q)*136 + n*8];
      *(ushort8*)(buf + tile*12288 + (long)kc*512 + lp*8) = v;
    }
  }
}

// ================= VQ: zero-LDS zero-barrier register-frag MFMA + argmin =================
// grid 4096 (bid = rb*16 + cblk; cblk%8 -> XCD, B slice L2-resident). 256 thr = 4 waves (2x2).
// Wave tile 64 rows x 64 codes (4x4 of 16x16x32). K = 2304 (3 segments of 768).
__global__ __launch_bounds__(256, 3)
void vq_mfma(const u16* __restrict__ xqh, const u16* __restrict__ xql,
             const u16* __restrict__ cbh, const u16* __restrict__ cbl,
             const float* __restrict__ cbn, unsigned long long* __restrict__ keys) {
  const int bid = blockIdx.x;
  const int rb = bid >> 4, cblk = bid & 15;
  const int tid = threadIdx.x, lane = tid & 63, w = tid >> 6;
  const int n = lane & 15, q = lane >> 4;
  const int wr = w & 1, wc = w >> 1;
  const int rT0 = rb*8 + wr*4;        // global rowTile for rt=0 (of 2048)
  const int cT0 = cblk*8 + wc*4;      // global codeTile for ct=0 (of 128)

  f32x4 acc[4][4];
#pragma unroll
  for (int a = 0; a < 4; ++a)
#pragma unroll
    for (int b2 = 0; b2 < 4; ++b2) acc[a][b2] = (f32x4){0.f, 0.f, 0.f, 0.f};

  half8 A0[4], B0[4], A1[4], B1[4];

  auto loadK = [&](int kc, half8 (&A)[4], half8 (&B)[4]) {
    const int seg = (kc >= 48) ? 2 : ((kc >= 24) ? 1 : 0);
    const int kk = kc - seg*24;
    const u16* ab = (seg == 1) ? xql : xqh;
    const u16* bb = (seg == 2) ? cbl : cbh;
    const u16* pa = ab + ((long)rT0*24 + kk)*512 + lane*8;
    const u16* pb = bb + ((long)cT0*24 + kk)*512 + lane*8;
#pragma unroll
    for (int i = 0; i < 4; ++i) {
      A[i] = *(const half8*)(pa + (long)i*12288);   // next rowTile: 24 KB stride
      B[i] = *(const half8*)(pb + (long)i*12288);
    }
  };
  auto mfmaSet = [&](half8 (&A)[4], half8 (&B)[4]) {
#pragma unroll
    for (int rt = 0; rt < 4; ++rt)
#pragma unroll
      for (int ct = 0; ct < 4; ++ct)
        acc[rt][ct] = mfmaF16(A[rt], B[ct], acc[rt][ct]);
  };

  loadK(0, A0, B0);
  for (int kc2 = 0; kc2 < 36; ++kc2) {
    const int kc = kc2 * 2;
    loadK(kc + 1, A1, B1);
    mfmaSet(A0, B0);
    if (kc2 < 35) loadK(kc + 2, A0, B0);
    mfmaSet(A1, B1);
  }

  // argmin epilogue: lane holds (row = rt*16 + q*4 + reg [+wr*64], code = ct*16 + n [+wc*64])
  float cbv[4];
#pragma unroll
  for (int ct = 0; ct < 4; ++ct) cbv[ct] = cbn[(cT0 + ct)*16 + n];
#pragma unroll
  for (int rt = 0; rt < 4; ++rt) {
#pragma unroll
    for (int reg = 0; reg < 4; ++reg) {
      float bd = 3.4e38f; int bi = 0;
#pragma unroll
      for (int ct = 0; ct < 4; ++ct) {
        float d = cbv[ct] - 2.0f * acc[rt][ct][reg];
        int code = (cT0 + ct)*16 + n;
        if (d < bd) { bd = d; bi = code; }
      }
      unsigned long long k = pack_key(bd, bi);
      unsigned long long v;
      v = __shfl_xor(k, 1); k = (v < k) ? v : k;
      v = __shfl_xor(k, 2); k = (v < k) ? v : k;
      v = __shfl_xor(k, 4); k = (v < k) ? v : k;
      v = __shfl_xor(k, 8); k = (v < k) ? v : k;
      if (n == 0) {
        int row = (rT0 + rt)*16 + q*4 + reg;
        atomicMin(&keys[row], k);
      }
    }
  }
}

__global__ void unpack_idx(const unsigned long long* __restrict__ keys,
                           int* __restrict__ idxv, float* __restrict__ outIdx) {
  int r = blockIdx.x * 256 + threadIdx.x;
  unsigned long long u = keys[r];
  int id = (int)(unsigned int)(u & 0xFFFFFFFFull);
  idxv[r] = id;
  outIdx[r] = (float)id;
}

// ================= fused gate + tail output (verified rounds 0/3/4/5) =================
__global__ __launch_bounds__(256)
void fuse_out(const float* __restrict__ src, const int* __restrict__ idxv,
              const float* __restrict__ gA, const float* __restrict__ uvec,
              const float* __restrict__ Mm, const float* __restrict__ tailcode,
              float* __restrict__ out) {
  __shared__ float ss[32][257];
  __shared__ float s0s[32];
  __shared__ int ids[32];
  const int tid = threadIdx.x;
  const int rb = blockIdx.x * 32;
  const int b = rb >> 10;
  const int p0 = rb & 1023;
#pragma unroll
  for (int qq = 0; qq < 32; ++qq)
    ss[qq][tid] = src[(long)(p0 + qq) * (BSZ*HID) + b*HID + tid];
  if (tid < 32) ids[tid] = idxv[rb + tid];
  __syncthreads();
  {
    const int wv = tid >> 6, lane = tid & 63;
    for (int qq = 0; qq < 8; ++qq) {
      int qp = wv*8 + qq;
      float a0 = 0.f, a1 = 0.f;
#pragma unroll
      for (int i = 0; i < 4; ++i) {
        float v = ss[qp][lane + 64*i];
        a0 += v * uvec[lane + 64*i];
        a1 += v * uvec[HID + lane + 64*i];
      }
#pragma unroll
      for (int off = 32; off; off >>= 1) { a0 += __shfl_down(a0, off); a1 += __shfl_down(a1, off); }
      if (lane == 0) {
        int id = ids[qp];
        float l0 = gA[id] + a0;
        float l1 = gA[NCODE + id] + a1;
        s0s[qp] = 1.0f / (1.0f + expf(l1 - l0));
      }
    }
  }
  __syncthreads();
  const int qg = tid >> 5, cg = tid & 31;
  const int q0 = qg * 4, c0 = cg * 8;
  float acc[4][8] = {};
  for (int cp = 0; cp < HID; ++cp) {
    float4 m0 = *(const float4*)(Mm + cp*HID + c0);
    float4 m1 = *(const float4*)(Mm + cp*HID + c0 + 4);
    float mm[8] = {m0.x,m0.y,m0.z,m0.w,m1.x,m1.y,m1.z,m1.w};
#pragma unroll
    for (int i = 0; i < 4; ++i) {
      float sv = ss[q0+i][cp];
#pragma unroll
      for (int j = 0; j < 8; ++j) acc[i][j] += sv * mm[j];
    }
  }
#pragma unroll
  for (int i = 0; i < 4; ++i) {
    int qp = q0 + i;
    int id = ids[qp];
    float s0 = s0s[qp], s1 = 1.0f - s0;
    const float* tc = tailcode + (long)id*HID + c0;
    float* op = out + (long)(p0+qp)*(BSZ*HID) + b*HID + c0;
    float4 o0, o1;
    o0.x = s0*tc[0] + s1*acc[i][0]; o0.y = s0*tc[1] + s1*acc[i][1];
    o0.z = s0*tc[2] + s1*acc[i][2]; o0.w = s0*tc[3] + s1*acc[i][3];
    o1.x = s0*tc[4] + s1*acc[i][4]; o1.y = s0*tc[5] + s1*acc[i][5];
    o1.z = s0*tc[6] + s1*acc[i][6]; o1.w = s0*tc[7] + s1*acc[i][7];
    *(float4*)(op) = o0; *(float4*)(op+4) = o1;
  }
}

// ================= launch =================
extern "C" void kernel_launch(void* const* d_in, const int* in_sizes, int n_in,
                              void* d_out, int out_size, void* d_ws, size_t ws_size,
                              hipStream_t stream) {
  const float* src    = (const float*)d_in[0];
  const float* cb     = (const float*)d_in[1];
  const float* w_head = (const float*)d_in[2];
  const float* w_tail = (const float*)d_in[3];
  const float* w_pos  = (const float*)d_in[4];
  const float* b_pos  = (const float*)d_in[5];
  const float* w_gate = (const float*)d_in[6];
  float* out = (float*)d_out;

  char* wsp = (char*)d_ws;
  size_t off = 0;
  auto alloc = [&](size_t bytes) {
    off = (off + 255) & ~(size_t)255;
    void* p = wsp + off; off += bytes; return p;
  };
  u16* xqh = (u16*)alloc((size_t)BSZ*TOKD*NVIS*2);  // 50.3 MB
  u16* xql = (u16*)alloc((size_t)BSZ*TOKD*NVIS*2);  // 50.3 MB
  u16* cbh = (u16*)alloc((size_t)NCODE*TOKD*2);
  u16* cbl = (u16*)alloc((size_t)NCODE*TOKD*2);
  u16* whh = (u16*)alloc((size_t)TOKD*HID*2);
  u16* whl = (u16*)alloc((size_t)TOKD*HID*2);
  float* cbn      = (float*)alloc((size_t)NCODE*4);
  float* Gt       = (float*)alloc((size_t)TOKD*HID*4);
  float* g2       = (float*)alloc((size_t)2*TOKD*4);
  float* ct0      = (float*)alloc((size_t)HID*4);
  float* cg       = (float*)alloc((size_t)2*4);
  float* tailcode = (float*)alloc((size_t)NCODE*HID*4);
  float* gA       = (float*)alloc((size_t)2*NCODE*4);
  float* Mm       = (float*)alloc((size_t)HID*HID*4);
  float* uvec     = (float*)alloc((size_t)2*HID*4);
  unsigned long long* keys = (unsigned long long*)alloc((size_t)NPIX*8);
  int* idxv       = (int*)alloc((size_t)NPIX*4);
  (void)ws_size; (void)in_sizes; (void)n_in; (void)out_size;

  prep1<<<8455, 256, 0, stream>>>(cb, w_head, w_tail, w_pos, w_gate, b_pos,
                                  cbh, cbl, whh, whl, cbn, Mm, uvec, Gt, g2, ct0, cg);
  retile<<<NCODE/16, 256, 0, stream>>>(cbh, cbl);          // codebook -> frag-tiled
  prep2<<<NCODE/8, 256, 0, stream>>>(cb, Gt, ct0, g2, cg, tailcode, gA);

  head_mfma<<<dim3(TOKD/128, NVIS/128, BSZ), 256, 0, stream>>>(whh, whl, src, xqh, xql);
  retile<<<NPIX/16, 256, 0, stream>>>(xqh, xql);           // xq -> frag-tiled (in place)

  hipMemsetAsync(keys, 0xFF, (size_t)NPIX*8, stream);
  vq_mfma<<<4096, 256, 0, stream>>>(xqh, xql, cbh, cbl, cbn, keys);
  unpack_idx<<<NPIX/256, 256, 0, stream>>>(keys, idxv, out + (size_t)NVIS*BSZ*HID);

  fuse_out<<<NPIX/32, 256, 0, stream>>>(src, idxv, gA, uvec, Mm, tailcode, out);
}

// Round 7
// 743.864 us; speedup vs baseline: 1.3545x; 1.0262x over previous
//
#include <hip/hip_runtime.h>
#include <cstdint>

#define BSZ 32
#define NVIS 1024
#define HID 256
#define TOKD 768
#define NCODE 2048
#define NPIX 32768

typedef unsigned short u16;
typedef _Float16 half8 __attribute__((ext_vector_type(8)));
typedef unsigned short ushort8 __attribute__((ext_vector_type(8)));
using f32x4 = __attribute__((ext_vector_type(4))) float;

#define AS1 __attribute__((address_space(1)))
#define AS3 __attribute__((address_space(3)))

__device__ __forceinline__ f32x4 mfmaF16(half8 a, half8 b, f32x4 c) {
  return __builtin_amdgcn_mfma_f32_16x16x32_f16(a, b, c, 0, 0, 0);
}

__device__ __forceinline__ unsigned long long pack_key(float d, int idx) {
  unsigned int b = __float_as_uint(d);
  b = (b & 0x80000000u) ? ~b : (b | 0x80000000u);  // monotonic float->uint
  return ((unsigned long long)b << 32) | (unsigned int)idx;
}

__device__ __forceinline__ void split16(float v, u16& h, u16& l) {
  union { _Float16 f; u16 u; } a, b;
  a.f = (_Float16)v;
  float hf = (float)a.f;
  b.f = (_Float16)(v - hf);
  h = a.u; l = b.u;
}

// ================= prep1: all weights-only precompute, one launch =================
__global__ __launch_bounds__(256)
void prep1(const float* __restrict__ cb, const float* __restrict__ wh,
           const float* __restrict__ wt, const float* __restrict__ wp,
           const float* __restrict__ wg, const float* __restrict__ bp,
           u16* __restrict__ cbh, u16* __restrict__ cbl,
           u16* __restrict__ whh, u16* __restrict__ whl,
           float* __restrict__ cbn, float* __restrict__ Mm, float* __restrict__ uv,
           float* __restrict__ Gt, float* __restrict__ g2,
           float* __restrict__ ct0, float* __restrict__ cg) {
  const int bid = blockIdx.x, tid = threadIdx.x;
  if (bid < 6144) {                       // split cb
    int i = bid*256 + tid;
    u16 h, l; split16(cb[i], h, l);
    cbh[i] = h; cbl[i] = l;
  } else if (bid < 6912) {                // split w_head
    int i = (bid - 6144)*256 + tid;
    u16 h, l; split16(wh[i], h, l);
    whh[i] = h; whl[i] = l;
  } else if (bid < 7424) {                // code norms
    int n = (bid - 6912)*4 + (tid >> 6);
    int lane = tid & 63;
    float a = 0.f;
#pragma unroll
    for (int i = 0; i < 12; ++i) { float v = cb[(long)n*TOKD + lane + 64*i]; a += v*v; }
#pragma unroll
    for (int off = 32; off; off >>= 1) a += __shfl_down(a, off);
    if (lane == 0) cbn[n] = a;
  } else if (bid < 7680) {                // make_M
    int c2 = bid - 7424, c1 = tid;
    float acc = 0.f;
    for (int t = 0; t < TOKD; ++t) acc += wh[t*HID + c1] * wt[(long)c2*TOKD + t];
    Mm[c1*HID + c2] = acc;
  } else if (bid < 7682) {                // make_u
    int o = bid - 7680, c1 = tid;
    float acc = 0.f;
    for (int t = 0; t < TOKD; ++t) acc += wh[t*HID + c1] * wg[o*(2*TOKD) + TOKD + t];
    uv[o*HID + c1] = acc;
  } else if (bid < 8450) {                // make_Gt
    int rbid = bid - 7682;
    int c = rbid & 255, part = rbid >> 8;
    int tp = part*256 + tid;
    float acc = 0.f;
    for (int t = 0; t < TOKD; ++t) acc += wt[(long)c*TOKD + t] * wp[(long)t*TOKD + tp];
    Gt[(long)tp*HID + c] = acc;
  } else if (bid < 8453) {                // g2
    int tp = (bid - 8450)*256 + tid;
    float a0 = 0.f, a1 = 0.f;
    for (int t = 0; t < TOKD; ++t) {
      float wv = wp[(long)t*TOKD + tp];
      a0 += wv * wg[t];
      a1 += wv * wg[2*TOKD + t];
    }
    g2[tp] = a0; g2[TOKD + tp] = a1;
  } else if (bid < 8454) {                // ct0
    int c = tid;
    float a = 0.f;
    for (int t = 0; t < TOKD; ++t) a += bp[t] * wt[(long)c*TOKD + t];
    ct0[c] = a;
  } else {                                // cg
    int o = tid >> 6, lane = tid & 63;
    if (o < 2) {
      float a = 0.f;
      for (int t = lane; t < TOKD; t += 64) a += bp[t] * wg[o*(2*TOKD) + t];
#pragma unroll
      for (int off = 32; off; off >>= 1) a += __shfl_down(a, off);
      if (lane == 0) cg[o] = a;
    }
  }
}

// ================= prep2: tailcode + gA from shared cb tile =================
__global__ __launch_bounds__(256)
void prep2(const float* __restrict__ cb, const float* __restrict__ Gt,
           const float* __restrict__ ct0, const float* __restrict__ g2,
           const float* __restrict__ cg, float* __restrict__ tc,
           float* __restrict__ gA) {
  __shared__ float cbs[8][TOKD];
  const int n0 = blockIdx.x * 8, tid = threadIdx.x;
  for (int i = tid; i < 8*TOKD; i += 256) cbs[i / TOKD][i % TOKD] = cb[(long)n0*TOKD + i];
  __syncthreads();
  float acc[8] = {};
  for (int t = 0; t < TOKD; ++t) {
    float gv = Gt[(long)t*HID + tid];
#pragma unroll
    for (int i = 0; i < 8; ++i) acc[i] += cbs[i][t] * gv;
  }
  float c0v = ct0[tid];
#pragma unroll
  for (int i = 0; i < 8; ++i) tc[(long)(n0+i)*HID + tid] = acc[i] + c0v;
  {
    int i = tid >> 5, l32 = tid & 31;
    float a0 = 0.f, a1 = 0.f;
    for (int t = l32; t < TOKD; t += 32) {
      float cv = cbs[i][t];
      a0 += cv * g2[t];
      a1 += cv * g2[TOKD + t];
    }
#pragma unroll
    for (int off = 16; off; off >>= 1) { a0 += __shfl_down(a0, off); a1 += __shfl_down(a1, off); }
    if (l32 == 0) { gA[n0+i] = a0 + cg[0]; gA[NCODE + n0+i] = a1 + cg[1]; }
  }
}

// ================= head GEMM (round-4 verified, row-major coalesced stores) =================
__global__ __launch_bounds__(256)
void head_mfma(const u16* __restrict__ whh, const u16* __restrict__ whl,
               const float* __restrict__ src,
               u16* __restrict__ xqh, u16* __restrict__ xql) {
  __shared__ u16 SM[32768] __attribute__((aligned(16)));   // 64 KB
  u16* Ah = SM;            // [2][4096]
  u16* Al = SM + 8192;
  u16* Bh = SM + 16384;
  u16* Bl = SM + 24576;
  const int tid = threadIdx.x, lane = tid & 63, w = tid >> 6;
  const int n = lane & 15, q = lane >> 4;
  const int rh = w & 1, ch = w >> 1;
  const int obase = blockIdx.x * 128, pbase = blockIdx.y * 128, b = blockIdx.z;

  auto stageA = [&](int kc, int buf) {
#pragma unroll
    for (int is = 0; is < 2; ++is) {
      int c = is*256 + tid;
      int t = c >> 6, qq = (c >> 4) & 3, nn = c & 15;
      long off = (long)(obase + t*16 + nn)*HID + kc*32 + qq*8;
      __builtin_amdgcn_global_load_lds((AS1 void*)(whh + off),
          (AS3 void*)&Ah[buf*4096 + c*8], 16, 0, 0);
      __builtin_amdgcn_global_load_lds((AS1 void*)(whl + off),
          (AS3 void*)&Al[buf*4096 + c*8], 16, 0, 0);
    }
  };
  auto stageB = [&](int kc, int buf) {
#pragma unroll
    for (int is = 0; is < 2; ++is) {
      int c = is*256 + tid;
      int t = c >> 6, qq = (c >> 4) & 3, nn = c & 15;
      const float* gp = src + ((long)(pbase + t*16 + nn)*BSZ + b)*HID + kc*32 + qq*8;
      float4 v0 = *(const float4*)gp;
      float4 v1 = *(const float4*)(gp + 4);
      float vv[8] = {v0.x, v0.y, v0.z, v0.w, v1.x, v1.y, v1.z, v1.w};
      ushort8 hv, lv;
#pragma unroll
      for (int j = 0; j < 8; ++j) { u16 hs, ls; split16(vv[j], hs, ls); hv[j] = hs; lv[j] = ls; }
      *(ushort8*)&Bh[buf*4096 + c*8] = hv;
      *(ushort8*)&Bl[buf*4096 + c*8] = lv;
    }
  };

  f32x4 acc[4][4];
#pragma unroll
  for (int i = 0; i < 4; ++i)
#pragma unroll
    for (int j = 0; j < 4; ++j) acc[i][j] = (f32x4){0.f, 0.f, 0.f, 0.f};

  stageA(0, 0); stageB(0, 0);
  __syncthreads();

  for (int kt = 0; kt < HID/32; ++kt) {
    const int buf = kt & 1;
    if (kt + 1 < HID/32) { stageA(kt + 1, buf ^ 1); stageB(kt + 1, buf ^ 1); }
    half8 af[4][2], bf[4][2];
#pragma unroll
    for (int rt = 0; rt < 4; ++rt) {
      int idx = buf*4096 + ((rh*4 + rt)*64 + q*16 + n)*8;
      af[rt][0] = *(const half8*)&Ah[idx];
      af[rt][1] = *(const half8*)&Al[idx];
    }
#pragma unroll
    for (int ct = 0; ct < 4; ++ct) {
      int idx = buf*4096 + ((ch*4 + ct)*64 + q*16 + n)*8;
      bf[ct][0] = *(const half8*)&Bh[idx];
      bf[ct][1] = *(const half8*)&Bl[idx];
    }
#pragma unroll
    for (int rt = 0; rt < 4; ++rt)
#pragma unroll
      for (int ct = 0; ct < 4; ++ct) {
        acc[rt][ct] = mfmaF16(af[rt][0], bf[ct][0], acc[rt][ct]);
        acc[rt][ct] = mfmaF16(af[rt][0], bf[ct][1], acc[rt][ct]);
        acc[rt][ct] = mfmaF16(af[rt][1], bf[ct][0], acc[rt][ct]);
      }
    __syncthreads();
  }

#pragma unroll
  for (int pass = 0; pass < 2; ++pass) {
    u16* dst = pass ? xql : xqh;
#pragma unroll
    for (int rt = 0; rt < 4; ++rt)
#pragma unroll
      for (int ct = 0; ct < 4; ++ct)
#pragma unroll
        for (int reg = 0; reg < 4; ++reg) {
          u16 hs, ls; split16(acc[rt][ct][reg], hs, ls);
          int ol = rh*64 + rt*16 + q*4 + reg;
          int pl = ch*64 + ct*16 + n;
          SM[ol*136 + pl] = pass ? ls : hs;
        }
    __syncthreads();
#pragma unroll
    for (int s = 0; s < 8; ++s) {
      int cc = tid*8 + s;
      int o = cc >> 4, p8 = cc & 15;
      ushort8 v = *(const ushort8*)&SM[o*136 + p8*8];
      *(ushort8*)(dst + ((long)b*TOKD + obase + o)*NVIS + pbase + p8*8) = v;
    }
    __syncthreads();
  }
}

// ================= retile: in-place row-major -> MFMA-fragment-tiled =================
__global__ __launch_bounds__(256)
void retile(u16* __restrict__ bufH, u16* __restrict__ bufL) {
  __shared__ u16 T[96*136] __attribute__((aligned(16)));
  const long tile = blockIdx.x;
  const int tid = threadIdx.x;
#pragma unroll
  for (int pass = 0; pass < 2; ++pass) {
    u16* buf = pass ? bufL : bufH;
    if (pass) __syncthreads();
#pragma unroll
    for (int i = 0; i < 6; ++i) {
      int g = i*256 + tid;
      int row = g / 96, c16 = g % 96;
      ushort8 v = *(const ushort8*)(buf + tile*12288 + row*768 + c16*8);
      *(ushort8*)&T[c16*136 + row*8] = v;
    }
    __syncthreads();
#pragma unroll
    for (int i = 0; i < 6; ++i) {
      int g = i*256 + tid;
      int kc = g >> 6, lp = g & 63;
      int q = lp >> 4, n = lp & 15;
      ushort8 v = *(const ushort8*)&T[(kc*4 + q)*136 + n*8];
      *(ushort8*)(buf + tile*12288 + (long)kc*512 + lp*8) = v;
    }
  }
}

// ================= VQ: zero-LDS register-frag MFMA, DEPTH-4 pipeline + argmin =================
// grid 4096 (bid = rb*16 + cblk; cblk%8 -> XCD, B slice L2-resident). 256 thr = 4 waves (2x2).
// Wave tile 64 rows x 64 codes (4x4 of 16x16x32). K = 2304 (3 segments of 768), 72 kc-steps.
#define LOADK(kc_, Ar, Br)                                              \
  {                                                                     \
    const int kcv = (kc_);                                              \
    const int seg = (kcv >= 48) ? 2 : ((kcv >= 24) ? 1 : 0);            \
    const int kk = kcv - seg*24;                                        \
    const u16* pa = ((seg == 1) ? pal : pah) + kk*512;                  \
    const u16* pb = ((seg == 2) ? pbl : pbh) + kk*512;                  \
    _Pragma("unroll")                                                   \
    for (int i = 0; i < 4; ++i) {                                       \
      Ar[i] = *(const half8*)(pa + (long)i*12288);                      \
      Br[i] = *(const half8*)(pb + (long)i*12288);                      \
    }                                                                   \
  }

#define MFMASET(Ar, Br)                                                 \
  {                                                                     \
    _Pragma("unroll")                                                   \
    for (int rt = 0; rt < 4; ++rt)                                      \
      _Pragma("unroll")                                                 \
      for (int ct = 0; ct < 4; ++ct)                                    \
        acc[rt][ct] = mfmaF16(Ar[rt], Br[ct], acc[rt][ct]);             \
  }

__global__ __launch_bounds__(256, 2)
void vq_mfma(const u16* __restrict__ xqh, const u16* __restrict__ xql,
             const u16* __restrict__ cbh, const u16* __restrict__ cbl,
             const float* __restrict__ cbn, unsigned long long* __restrict__ keys) {
  const int bid = blockIdx.x;
  const int rb = bid >> 4, cblk = bid & 15;
  const int tid = threadIdx.x, lane = tid & 63, w = tid >> 6;
  const int n = lane & 15, q = lane >> 4;
  const int wr = w & 1, wc = w >> 1;
  const int rT0 = rb*8 + wr*4;        // global rowTile for rt=0 (of 2048)
  const int cT0 = cblk*8 + wc*4;      // global codeTile for ct=0 (of 128)

  const u16* pah = xqh + (long)rT0*12288 + lane*8;
  const u16* pal = xql + (long)rT0*12288 + lane*8;
  const u16* pbh = cbh + (long)cT0*12288 + lane*8;
  const u16* pbl = cbl + (long)cT0*12288 + lane*8;

  f32x4 acc[4][4];
#pragma unroll
  for (int a = 0; a < 4; ++a)
#pragma unroll
    for (int b2 = 0; b2 < 4; ++b2) acc[a][b2] = (f32x4){0.f, 0.f, 0.f, 0.f};

  half8 A0[4], A1[4], A2[4], A3[4];
  half8 B0[4], B1[4], B2[4], B3[4];

  LOADK(0, A0, B0);
  LOADK(1, A1, B1);
  LOADK(2, A2, B2);

  for (int kc2 = 0; kc2 < 18; ++kc2) {
    const int kc = kc2 * 4;
    if (kc + 3 < 72) LOADK(kc + 3, A3, B3);
    MFMASET(A0, B0);
    if (kc + 4 < 72) LOADK(kc + 4, A0, B0);
    MFMASET(A1, B1);
    if (kc + 5 < 72) LOADK(kc + 5, A1, B1);
    MFMASET(A2, B2);
    if (kc + 6 < 72) LOADK(kc + 6, A2, B2);
    MFMASET(A3, B3);
  }

  // argmin epilogue: lane holds (row = rt*16 + q*4 + reg, code = ct*16 + n) in global tiles
  float cbv[4];
#pragma unroll
  for (int ct = 0; ct < 4; ++ct) cbv[ct] = cbn[(cT0 + ct)*16 + n];
#pragma unroll
  for (int rt = 0; rt < 4; ++rt) {
#pragma unroll
    for (int reg = 0; reg < 4; ++reg) {
      float bd = 3.4e38f; int bi = 0;
#pragma unroll
      for (int ct = 0; ct < 4; ++ct) {
        float d = cbv[ct] - 2.0f * acc[rt][ct][reg];
        int code = (cT0 + ct)*16 + n;
        if (d < bd) { bd = d; bi = code; }
      }
      unsigned long long k = pack_key(bd, bi);
      unsigned long long v;
      v = __shfl_xor(k, 1); k = (v < k) ? v : k;
      v = __shfl_xor(k, 2); k = (v < k) ? v : k;
      v = __shfl_xor(k, 4); k = (v < k) ? v : k;
      v = __shfl_xor(k, 8); k = (v < k) ? v : k;
      if (n == 0) {
        int row = (rT0 + rt)*16 + q*4 + reg;
        atomicMin(&keys[row], k);
      }
    }
  }
}

// ================= fused gate + tail output (+ index unpack folded in) =================
__global__ __launch_bounds__(256)
void fuse_out(const float* __restrict__ src, const unsigned long long* __restrict__ keys,
              const float* __restrict__ gA, const float* __restrict__ uvec,
              const float* __restrict__ Mm, const float* __restrict__ tailcode,
              float* __restrict__ out, float* __restrict__ outIdx) {
  __shared__ float ss[32][257];
  __shared__ float s0s[32];
  __shared__ int ids[32];
  const int tid = threadIdx.x;
  const int rb = blockIdx.x * 32;
  const int b = rb >> 10;
  const int p0 = rb & 1023;
#pragma unroll
  for (int qq = 0; qq < 32; ++qq)
    ss[qq][tid] = src[(long)(p0 + qq) * (BSZ*HID) + b*HID + tid];
  if (tid < 32) {
    unsigned long long u = keys[rb + tid];
    int id = (int)(unsigned int)(u & 0xFFFFFFFFull);
    ids[tid] = id;
    outIdx[rb + tid] = (float)id;
  }
  __syncthreads();
  {
    const int wv = tid >> 6, lane = tid & 63;
    for (int qq = 0; qq < 8; ++qq) {
      int qp = wv*8 + qq;
      float a0 = 0.f, a1 = 0.f;
#pragma unroll
      for (int i = 0; i < 4; ++i) {
        float v = ss[qp][lane + 64*i];
        a0 += v * uvec[lane + 64*i];
        a1 += v * uvec[HID + lane + 64*i];
      }
#pragma unroll
      for (int off = 32; off; off >>= 1) { a0 += __shfl_down(a0, off); a1 += __shfl_down(a1, off); }
      if (lane == 0) {
        int id = ids[qp];
        float l0 = gA[id] + a0;
        float l1 = gA[NCODE + id] + a1;
        s0s[qp] = 1.0f / (1.0f + expf(l1 - l0));
      }
    }
  }
  __syncthreads();
  const int qg = tid >> 5, cg = tid & 31;
  const int q0 = qg * 4, c0 = cg * 8;
  float acc[4][8] = {};
  for (int cp = 0; cp < HID; ++cp) {
    float4 m0 = *(const float4*)(Mm + cp*HID + c0);
    float4 m1 = *(const float4*)(Mm + cp*HID + c0 + 4);
    float mm[8] = {m0.x,m0.y,m0.z,m0.w,m1.x,m1.y,m1.z,m1.w};
#pragma unroll
    for (int i = 0; i < 4; ++i) {
      float sv = ss[q0+i][cp];
#pragma unroll
      for (int j = 0; j < 8; ++j) acc[i][j] += sv * mm[j];
    }
  }
#pragma unroll
  for (int i = 0; i < 4; ++i) {
    int qp = q0 + i;
    int id = ids[qp];
    float s0 = s0s[qp], s1 = 1.0f - s0;
    const float* tc = tailcode + (long)id*HID + c0;
    float* op = out + (long)(p0+qp)*(BSZ*HID) + b*HID + c0;
    float4 o0, o1;
    o0.x = s0*tc[0] + s1*acc[i][0]; o0.y = s0*tc[1] + s1*acc[i][1];
    o0.z = s0*tc[2] + s1*acc[i][2]; o0.w = s0*tc[3] + s1*acc[i][3];
    o1.x = s0*tc[4] + s1*acc[i][4]; o1.y = s0*tc[5] + s1*acc[i][5];
    o1.z = s0*tc[6] + s1*acc[i][6]; o1.w = s0*tc[7] + s1*acc[i][7];
    *(float4*)(op) = o0; *(float4*)(op+4) = o1;
  }
}

// ================= launch =================
extern "C" void kernel_launch(void* const* d_in, const int* in_sizes, int n_in,
                              void* d_out, int out_size, void* d_ws, size_t ws_size,
                              hipStream_t stream) {
  const float* src    = (const float*)d_in[0];
  const float* cb     = (const float*)d_in[1];
  const float* w_head = (const float*)d_in[2];
  const float* w_tail = (const float*)d_in[3];
  const float* w_pos  = (const float*)d_in[4];
  const float* b_pos  = (const float*)d_in[5];
  const float* w_gate = (const float*)d_in[6];
  float* out = (float*)d_out;

  char* wsp = (char*)d_ws;
  size_t off = 0;
  auto alloc = [&](size_t bytes) {
    off = (off + 255) & ~(size_t)255;
    void* p = wsp + off; off += bytes; return p;
  };
  u16* xqh = (u16*)alloc((size_t)BSZ*TOKD*NVIS*2);  // 50.3 MB
  u16* xql = (u16*)alloc((size_t)BSZ*TOKD*NVIS*2);  // 50.3 MB
  u16* cbh = (u16*)alloc((size_t)NCODE*TOKD*2);
  u16* cbl = (u16*)alloc((size_t)NCODE*TOKD*2);
  u16* whh = (u16*)alloc((size_t)TOKD*HID*2);
  u16* whl = (u16*)alloc((size_t)TOKD*HID*2);
  float* cbn      = (float*)alloc((size_t)NCODE*4);
  float* Gt       = (float*)alloc((size_t)TOKD*HID*4);
  float* g2       = (float*)alloc((size_t)2*TOKD*4);
  float* ct0      = (float*)alloc((size_t)HID*4);
  float* cg       = (float*)alloc((size_t)2*4);
  float* tailcode = (float*)alloc((size_t)NCODE*HID*4);
  float* gA       = (float*)alloc((size_t)2*NCODE*4);
  float* Mm       = (float*)alloc((size_t)HID*HID*4);
  float* uvec     = (float*)alloc((size_t)2*HID*4);
  unsigned long long* keys = (unsigned long long*)alloc((size_t)NPIX*8);
  (void)ws_size; (void)in_sizes; (void)n_in; (void)out_size;

  prep1<<<8455, 256, 0, stream>>>(cb, w_head, w_tail, w_pos, w_gate, b_pos,
                                  cbh, cbl, whh, whl, cbn, Mm, uvec, Gt, g2, ct0, cg);
  retile<<<NCODE/16, 256, 0, stream>>>(cbh, cbl);          // codebook -> frag-tiled
  prep2<<<NCODE/8, 256, 0, stream>>>(cb, Gt, ct0, g2, cg, tailcode, gA);

  head_mfma<<<dim3(TOKD/128, NVIS/128, BSZ), 256, 0, stream>>>(whh, whl, src, xqh, xql);
  retile<<<NPIX/16, 256, 0, stream>>>(xqh, xql);           // xq -> frag-tiled (in place)

  hipMemsetAsync(keys, 0xFF, (size_t)NPIX*8, stream);
  vq_mfma<<<4096, 256, 0, stream>>>(xqh, xql, cbh, cbl, cbn, keys);

  fuse_out<<<NPIX/32, 256, 0, stream>>>(src, keys, gA, uvec, Mm, tailcode,
                                        out, out + (size_t)NVIS*BSZ*HID);
}